// Round 3
// baseline (110.176 us; speedup 1.0000x reference)
//
#include <hip/hip_runtime.h>
#include <hip/hip_bf16.h>

#define EPS 1e-12f

typedef __bf16 bf16x8 __attribute__((ext_vector_type(8)));
typedef __bf16 bf16x4 __attribute__((ext_vector_type(4)));
typedef float  f32x4  __attribute__((ext_vector_type(4)));

// Problem constants: B=16, N=1024, M=12, F_atom=128, F_bond=32, F_out=128
//
// Two kernels (grid-barrier fusion measured 50 µs WORSE in round 1: per-wave
// agent fences serialize at the TCCs and the L2 invalidate kills atom
// residency). Fixed per-iteration harness costs pinned by rocprof: 256 MiB
// ws poison fill ~43 µs @78% HBM peak + ~30 µs restore/launch train. Kernel
// budget is ~25 µs; this round overlaps k_main's Phase-B p-load latency
// (~500-900 cy post-flush) under the L2 gather instead of stalling on it.

// ---------------------------------------------------------------------------
// K1: bond-norm chain -> p[row]; blocks 0..15 also transpose W -> Wt (bf16).
//    p = (prod_m x_m) / d^12, d = max(sum_m x_m, EPS), x_m = 1/||bond_m||^2
// Wave w owns 8 bond rows (12 KB): 12 fully-coalesced 1-KB f32x4 wave loads,
// 8-lane segmented shfl_xor reduce. ~25 MB cold HBM => ~4-5 µs, near floor.
// ---------------------------------------------------------------------------
__global__ __launch_bounds__(512) void k_bond(const float* __restrict__ bond,
                                              const float* __restrict__ W,
                                              float* __restrict__ p,
                                              __bf16* __restrict__ Wt)
{
    __shared__ float xv[64][12];     // raw sum-of-squares per (row, m)
    const int t = threadIdx.x, blk = blockIdx.x;
    const int wave = t >> 6, lane = t & 63;

    const float* wbase = bond + (size_t)(blk * 64 + wave * 8) * 384;
#pragma unroll
    for (int i = 0; i < 12; ++i) {
        f32x4 v = __builtin_nontemporal_load((const f32x4*)(wbase + (i * 64 + lane) * 4));
        float s = v.x * v.x;
        s = fmaf(v.y, v.y, s);
        s = fmaf(v.z, v.z, s);
        s = fmaf(v.w, v.w, s);
        s += __shfl_xor(s, 1);
        s += __shfl_xor(s, 2);
        s += __shfl_xor(s, 4);
        if ((lane & 7) == 0) {
            const int g = i * 8 + (lane >> 3);      // 0..95 = row-in-wave*12 + m
            xv[wave * 8 + g / 12][g % 12] = s;
        }
    }

    // W (128x128 f32 [k][j]) -> Wt bf16 [j][k], blocks 0..15
    if (blk < 16) {
        const int e = (blk * 512 + t) * 2;          // even => both elems same k
        const int k = e >> 7, j = e & 127;
        float2 wv = *(const float2*)(W + e);
        Wt[j * 128 + k]       = (__bf16)wv.x;
        Wt[(j + 1) * 128 + k] = (__bf16)wv.y;
    }
    __syncthreads();

    // p = prod(x)/d^12, x_m = 1/ssq_m, d = max(sum_m x_m, EPS)
    if (t < 64) {
        float x[12], sum = 0.f, prod = 1.f;
#pragma unroll
        for (int m = 0; m < 12; ++m) x[m] = 1.0f / xv[t][m];
#pragma unroll
        for (int m = 0; m < 12; ++m) { sum += x[m]; prod *= x[m]; }
        const float d = fmaxf(sum, EPS);
        const float d2 = d * d, d3 = d2 * d, d6 = d3 * d3;
        p[blk * 64 + t] = prod / (d6 * d6);         // prod(x/d) = prod(x)/d^12
    }
}

// ---------------------------------------------------------------------------
// K2: scale + gather + MFMA. 64 rows/block, 512 threads, 256 blocks.
// Restructured: p loads ISSUED at top into registers (no sums), the 52-load
// L2 gather runs next and hides the p latency, then Phase B finishes from
// registers; gather results stay in regs until sScale is ready.
// XCD swizzle: lower 3 bits of blk = XCD residue; 2 batches/XCD (1 MB atom
// working set, L2-resident).
// ---------------------------------------------------------------------------
__global__ __launch_bounds__(512) void k_main(const float* __restrict__ atom,
                                              const int* __restrict__ adj,
                                              const float* __restrict__ p,
                                              const __bf16* __restrict__ Wt,
                                              const float* __restrict__ bias,
                                              float* __restrict__ out)
{
    __shared__ __bf16 uA[64][136];   // 17.4 KB; stride 136: 16B-aligned, benign banking
    __shared__ float  sScale[64] __attribute__((aligned(16)));
    __shared__ int    sAdj[64 * 12];
    __shared__ float  red[4];

    const int t = threadIdx.x;
    const int blk = blockIdx.x;
    const int b   = (blk & 7) | (((blk >> 7) & 1) << 3);
    const int nlo = ((blk >> 3) & 15) * 64;
    const int rowbase = b * 1024 + nlo;

    for (int idx = t; idx < 768; idx += 512) sAdj[idx] = adj[rowbase * 12 + idx];

    // ---- Phase B issue: p loads into live registers, summation deferred ----
    const int n0 = (t & 255) * 4;
    f32x4 pv[16];
    f32x4 pb = {1.f, 1.f, 1.f, 1.f};
    if (t < 256) {
#pragma unroll
        for (int bb = 0; bb < 16; ++bb) pv[bb] = *(const f32x4*)(p + bb * 1024 + n0);
        pb = *(const f32x4*)(p + b * 1024 + n0);
    }
    __syncthreads();                 // sAdj ready

    // ---- Phase C body: gather into registers (hides p-load latency) ----
    const int jc = (t & 31) * 4;
    const int rg = t >> 5;                         // 0..15
    const float* atomB = atom + (size_t)b * (1024 * 128);
    f32x4 ac[4], ow[4];
#pragma unroll
    for (int i = 0; i < 4; ++i) {
        const int r = rg + i * 16;
        f32x4 a = {0.f, 0.f, 0.f, 0.f};
#pragma unroll
        for (int m = 0; m < 12; ++m) {
            int idx = sAdj[r * 12 + m];
            a += *(const f32x4*)(atomB + (size_t)idx * 128 + jc);
        }
        ac[i] = a;
        ow[i] = *(const f32x4*)(atomB + (size_t)(nlo + r) * 128 + jc);
    }

    // ---- Phase B finish: r[n] = max(sum_bb p, EPS)/p[b,n]; scale = r/sum_n r
    f32x4 r4 = {0.f, 0.f, 0.f, 0.f};
    if (t < 256) {
        f32x4 cs = pv[0];
#pragma unroll
        for (int bb = 1; bb < 16; ++bb) cs += pv[bb];
        r4.x = fmaxf(cs.x, EPS) / pb.x;
        r4.y = fmaxf(cs.y, EPS) / pb.y;
        r4.z = fmaxf(cs.z, EPS) / pb.z;
        r4.w = fmaxf(cs.w, EPS) / pb.w;
        float S_part = r4.x + r4.y + r4.z + r4.w;
#pragma unroll
        for (int off = 32; off >= 1; off >>= 1) S_part += __shfl_xor(S_part, off);
        if ((t & 63) == 0) red[t >> 6] = S_part;
    }
    __syncthreads();
    if (t < 256) {
        const float invS = 1.0f / fmaxf(red[0] + red[1] + red[2] + red[3], EPS);
        if (n0 >= nlo && n0 < nlo + 64) *(f32x4*)&sScale[n0 - nlo] = r4 * invS;
    }
    __syncthreads();

    // ---- scale + bf16 pack -> LDS ----
#pragma unroll
    for (int i = 0; i < 4; ++i) {
        const int r = rg + i * 16;
        f32x4 u = (ow[i] + ac[i] * (1.0f / 12.0f)) * sScale[r];
        bf16x4 ub;
        ub.x = (__bf16)u.x; ub.y = (__bf16)u.y; ub.z = (__bf16)u.z; ub.w = (__bf16)u.w;
        *(bf16x4*)&uA[r][jc] = ub;
    }
    __syncthreads();

    // ---- Phase D: wave-pair wp owns rows wp*16..+15; half = n-tile half ----
    const int wave = t >> 6, lane = t & 63;
    const int wp = wave >> 1, half = wave & 1;
    const int r0 = wp * 16;
    const int quad = lane >> 4, lrow = lane & 15;

    bf16x8 aF[4];
#pragma unroll
    for (int kc = 0; kc < 4; ++kc)
        aF[kc] = *(const bf16x8*)&uA[r0 + lrow][kc * 32 + quad * 8];

    f32x4 acc[4];
#pragma unroll
    for (int q = 0; q < 4; ++q) acc[q] = (f32x4){0.f, 0.f, 0.f, 0.f};

#pragma unroll
    for (int q = 0; q < 4; ++q) {
        const int col = (half * 4 + q) * 16 + lrow;
        const __bf16* wb = Wt + col * 128 + quad * 8;
#pragma unroll
        for (int kc = 0; kc < 4; ++kc) {
            bf16x8 bF = *(const bf16x8*)(wb + kc * 32);
            acc[q] = __builtin_amdgcn_mfma_f32_16x16x32_bf16(aF[kc], bF, acc[q], 0, 0, 0);
        }
    }

    // ---- Epilogue: C/D layout col=lane&15, row=quad*4+i; NT stores ----
#pragma unroll
    for (int q = 0; q < 4; ++q) {
        const int col = (half * 4 + q) * 16 + lrow;
        const float bv = bias[col];
#pragma unroll
        for (int i = 0; i < 4; ++i) {
            const int r = r0 + quad * 4 + i;
            float v = fmaxf(acc[q][i] + bv, 0.f);
            __builtin_nontemporal_store(v, &out[(size_t)(rowbase + r) * 128 + col]);
        }
    }
}

// ---------------------------------------------------------------------------
extern "C" void kernel_launch(void* const* d_in, const int* in_sizes, int n_in,
                              void* d_out, int out_size, void* d_ws, size_t ws_size,
                              hipStream_t stream) {
    const float* atom = (const float*)d_in[0];
    const float* bond = (const float*)d_in[1];
    const int*   adj  = (const int*)d_in[2];
    const float* W    = (const float*)d_in[3];
    const float* bias = (const float*)d_in[4];
    float* out = (float*)d_out;

    char* ws = (char*)d_ws;
    float*  p  = (float*)ws;                       // 16384 f32 = 64 KB
    __bf16* Wt = (__bf16*)(ws + 65536);            // 16384 bf16 = 32 KB

    hipLaunchKernelGGL(k_bond, dim3(256), dim3(512), 0, stream, bond, W, p, Wt);
    hipLaunchKernelGGL(k_main, dim3(256), dim3(512), 0, stream, atom, adj, p, Wt, bias, out);
}

// Round 4
// 100.142 us; speedup vs baseline: 1.1002x; 1.1002x over previous
//
#include <hip/hip_runtime.h>
#include <hip/hip_bf16.h>

#define EPS 1e-12f

typedef __bf16 bf16x8 __attribute__((ext_vector_type(8)));
typedef __bf16 bf16x4 __attribute__((ext_vector_type(4)));
typedef float  f32x4  __attribute__((ext_vector_type(4)));

// Problem constants: B=16, N=1024, M=12, F_atom=128, F_bond=32, F_out=128
//
// Two kernels. Measured dead ends: grid-barrier fusion (round 1, +79 µs:
// per-wave agent fences serialize at TCCs, L2 inv kills atom residency);
// p-load register hoist across the gather (round 3, +9 µs: 68 live VGPRs
// force deep vmcnt drains). Harness fixed cost per iteration: 256 MiB ws
// poison @ ~43-45 µs (78% HBM) + restore train; cross-round noise ±3 µs.
//
// This round: round-2 structure + k_main at 512 blocks x 256 threads
// (2 blocks/CU co-resident = 16 waves/CU latency hiding; all threads
// active in the scale phase; ~10.5 KB LDS/block).

// ---------------------------------------------------------------------------
// K1: bond-norm chain -> p[row]; blocks 0..15 also transpose W -> Wt (bf16).
//    p = (prod_m x_m) / d^12, d = max(sum_m x_m, EPS), x_m = 1/||bond_m||^2
// Wave w owns 8 bond rows (12.3 KB): 12 fully-coalesced 1-KB f32x4 wave
// loads, 8-lane segmented shfl_xor reduce. 25 MB cold HBM => ~4.5 µs floor.
// ---------------------------------------------------------------------------
__global__ __launch_bounds__(512) void k_bond(const float* __restrict__ bond,
                                              const float* __restrict__ W,
                                              float* __restrict__ p,
                                              __bf16* __restrict__ Wt)
{
    __shared__ float xv[64][12];     // raw sum-of-squares per (row, m)
    const int t = threadIdx.x, blk = blockIdx.x;
    const int wave = t >> 6, lane = t & 63;

    const float* wbase = bond + (size_t)(blk * 64 + wave * 8) * 384;
#pragma unroll
    for (int i = 0; i < 12; ++i) {
        f32x4 v = __builtin_nontemporal_load((const f32x4*)(wbase + (i * 64 + lane) * 4));
        float s = v.x * v.x;
        s = fmaf(v.y, v.y, s);
        s = fmaf(v.z, v.z, s);
        s = fmaf(v.w, v.w, s);
        s += __shfl_xor(s, 1);
        s += __shfl_xor(s, 2);
        s += __shfl_xor(s, 4);
        if ((lane & 7) == 0) {
            const int g = i * 8 + (lane >> 3);      // 0..95 = row-in-wave*12 + m
            xv[wave * 8 + g / 12][g % 12] = s;
        }
    }

    // W (128x128 f32 [k][j]) -> Wt bf16 [j][k], blocks 0..15
    if (blk < 16) {
        const int e = (blk * 512 + t) * 2;          // even => both elems same k
        const int k = e >> 7, j = e & 127;
        float2 wv = *(const float2*)(W + e);
        Wt[j * 128 + k]       = (__bf16)wv.x;
        Wt[(j + 1) * 128 + k] = (__bf16)wv.y;
    }
    __syncthreads();

    // p = prod(x)/d^12, x_m = 1/ssq_m, d = max(sum_m x_m, EPS)
    if (t < 64) {
        float x[12], sum = 0.f, prod = 1.f;
#pragma unroll
        for (int m = 0; m < 12; ++m) x[m] = 1.0f / xv[t][m];
#pragma unroll
        for (int m = 0; m < 12; ++m) { sum += x[m]; prod *= x[m]; }
        const float d = fmaxf(sum, EPS);
        const float d2 = d * d, d3 = d2 * d, d6 = d3 * d3;
        p[blk * 64 + t] = prod / (d6 * d6);         // prod(x/d) = prod(x)/d^12
    }
}

// ---------------------------------------------------------------------------
// K2: scale + gather + MFMA. 32 rows/block, 256 threads, 512 blocks
// (2 blocks/CU co-resident -> 16 waves/CU). XCD swizzle: low 3 bits of blk =
// XCD residue; each XCD serves 2 batches (1 MB atom working set, L2-resident).
// ---------------------------------------------------------------------------
__global__ __launch_bounds__(256) void k_main(const float* __restrict__ atom,
                                              const int* __restrict__ adj,
                                              const float* __restrict__ p,
                                              const __bf16* __restrict__ Wt,
                                              const float* __restrict__ bias,
                                              float* __restrict__ out)
{
    __shared__ __bf16 uA[32][136];   // 8.7 KB; stride 136: 16B-aligned, benign banking
    __shared__ float  sScale[32] __attribute__((aligned(16)));
    __shared__ int    sAdj[32 * 12];
    __shared__ float  red[4];

    const int t = threadIdx.x;
    const int blk = blockIdx.x;                    // 512 = 8 xcd x 32 slot x 2 hi
    const int b   = (blk & 7) | (((blk >> 8) & 1) << 3);
    const int nlo = ((blk >> 3) & 31) * 32;
    const int rowbase = b * 1024 + nlo;

    for (int idx = t; idx < 384; idx += 256) sAdj[idx] = adj[rowbase * 12 + idx];

    // ---- Phase B: scale (all 256 threads, 4 n's each) ----
    // r[n] = max(sum_bb p[bb,n], EPS)/p[b,n]; scale = r / max(sum_n r, EPS)
    const int n0 = t * 4;
    f32x4 cs = {0.f, 0.f, 0.f, 0.f};
#pragma unroll
    for (int bb = 0; bb < 16; ++bb) cs += *(const f32x4*)(p + bb * 1024 + n0);
    f32x4 pb = *(const f32x4*)(p + b * 1024 + n0);
    f32x4 r4;
    r4.x = fmaxf(cs.x, EPS) / pb.x;
    r4.y = fmaxf(cs.y, EPS) / pb.y;
    r4.z = fmaxf(cs.z, EPS) / pb.z;
    r4.w = fmaxf(cs.w, EPS) / pb.w;
    float S_part = r4.x + r4.y + r4.z + r4.w;
#pragma unroll
    for (int off = 32; off >= 1; off >>= 1) S_part += __shfl_xor(S_part, off);
    if ((t & 63) == 0) red[t >> 6] = S_part;
    __syncthreads();
    {
        const float invS = 1.0f / fmaxf(red[0] + red[1] + red[2] + red[3], EPS);
        if (n0 >= nlo && n0 < nlo + 32) *(f32x4*)&sScale[n0 - nlo] = r4 * invS;
    }
    __syncthreads();

    // ---- Phase C: f32x4 gather; u = (own + accn/12) * scale -> bf16 LDS ----
    {
        const int jc = (t & 31) * 4;               // 4 cols/thread
        const int rg = t >> 5;                     // 8 row-groups
        const float* atomB = atom + (size_t)b * (1024 * 128);
#pragma unroll
        for (int i = 0; i < 4; ++i) {
            const int r = rg + i * 8;              // 0..31
            f32x4 a = {0.f, 0.f, 0.f, 0.f};
#pragma unroll
            for (int m = 0; m < 12; ++m) {
                int idx = sAdj[r * 12 + m];
                a += *(const f32x4*)(atomB + (size_t)idx * 128 + jc);
            }
            f32x4 own = *(const f32x4*)(atomB + (size_t)(nlo + r) * 128 + jc);
            f32x4 u = (own + a * (1.0f / 12.0f)) * sScale[r];
            bf16x4 ub;
            ub.x = (__bf16)u.x; ub.y = (__bf16)u.y; ub.z = (__bf16)u.z; ub.w = (__bf16)u.w;
            *(bf16x4*)&uA[r][jc] = ub;
        }
    }
    __syncthreads();

    // ---- Phase D: wave-pair wp owns rows wp*16..+15; half = n-tile half ----
    const int wave = t >> 6, lane = t & 63;
    const int wp = wave >> 1, half = wave & 1;
    const int r0 = wp * 16;
    const int quad = lane >> 4, lrow = lane & 15;

    bf16x8 aF[4];
#pragma unroll
    for (int kc = 0; kc < 4; ++kc)
        aF[kc] = *(const bf16x8*)&uA[r0 + lrow][kc * 32 + quad * 8];

    f32x4 acc[4];
#pragma unroll
    for (int q = 0; q < 4; ++q) acc[q] = (f32x4){0.f, 0.f, 0.f, 0.f};

#pragma unroll
    for (int q = 0; q < 4; ++q) {
        const int col = (half * 4 + q) * 16 + lrow;
        const __bf16* wb = Wt + col * 128 + quad * 8;
#pragma unroll
        for (int kc = 0; kc < 4; ++kc) {
            bf16x8 bF = *(const bf16x8*)(wb + kc * 32);
            acc[q] = __builtin_amdgcn_mfma_f32_16x16x32_bf16(aF[kc], bF, acc[q], 0, 0, 0);
        }
    }

    // ---- Epilogue: C/D layout col=lane&15, row=quad*4+i; NT stores ----
#pragma unroll
    for (int q = 0; q < 4; ++q) {
        const int col = (half * 4 + q) * 16 + lrow;
        const float bv = bias[col];
#pragma unroll
        for (int i = 0; i < 4; ++i) {
            const int r = r0 + quad * 4 + i;
            float v = fmaxf(acc[q][i] + bv, 0.f);
            __builtin_nontemporal_store(v, &out[(size_t)(rowbase + r) * 128 + col]);
        }
    }
}

// ---------------------------------------------------------------------------
extern "C" void kernel_launch(void* const* d_in, const int* in_sizes, int n_in,
                              void* d_out, int out_size, void* d_ws, size_t ws_size,
                              hipStream_t stream) {
    const float* atom = (const float*)d_in[0];
    const float* bond = (const float*)d_in[1];
    const int*   adj  = (const int*)d_in[2];
    const float* W    = (const float*)d_in[3];
    const float* bias = (const float*)d_in[4];
    float* out = (float*)d_out;

    char* ws = (char*)d_ws;
    float*  p  = (float*)ws;                       // 16384 f32 = 64 KB
    __bf16* Wt = (__bf16*)(ws + 65536);            // 16384 bf16 = 32 KB

    hipLaunchKernelGGL(k_bond, dim3(256), dim3(512), 0, stream, bond, W, p, Wt);
    hipLaunchKernelGGL(k_main, dim3(512), dim3(256), 0, stream, atom, adj, p, Wt, bias, out);
}